// Round 1
// baseline (144.058 us; speedup 1.0000x reference)
//
#include <hip/hip_runtime.h>
#include <hip/hip_bf16.h>

#define DHID 256
#define ROWS 64
#define THREADS 256
#define NROWS 131072

typedef __attribute__((ext_vector_type(8))) __bf16 bf16x8;
typedef __attribute__((ext_vector_type(4))) float f32x4;

// f32 -> bf16 bits, round-to-nearest-even
__device__ __forceinline__ unsigned short f2b(float f) {
    union { float f; unsigned u; } x; x.f = f;
    unsigned r = x.u + 0x7fffu + ((x.u >> 16) & 1u);
    return (unsigned short)(r >> 16);
}

// swizzled byte offset within a [64][256] bf16 LDS tile (T2-style XOR swizzle,
// breaks the 512B row-stride bank conflict on ds_read_b128 / ds_write_b64)
__device__ __forceinline__ int hswz(int row, int col) {
    return ((row << 9) + (col << 1)) ^ ((row & 7) << 4);
}

// ---- prep kernel 1: convert the three 256x256 f32 weight matrices to bf16 ----
__global__ void conv_w(const float* __restrict__ w0, const float* __restrict__ w1,
                       const float* __restrict__ w2, unsigned short* __restrict__ out) {
    int i = blockIdx.x * blockDim.x + threadIdx.x;   // 0..196607
    const float* src = (i < 65536) ? w0 : (i < 131072 ? w1 : w2);
    out[i] = f2b(src[i & 65535]);
}

// ---- prep kernel 2: M[k] = (dot(pn_k, Wout0), dot(pn_k, Wout1)), pn_k = proto_k/||proto_k|| ----
__global__ void make_m(const float* __restrict__ proto, const float* __restrict__ wout,
                       float2* __restrict__ M) {
    int k = blockIdx.x;       // 0..255
    int l = threadIdx.x;      // 0..63
    float s2 = 0.f, d0 = 0.f, d1 = 0.f;
#pragma unroll
    for (int q = 0; q < 4; ++q) {
        int c = l + 64 * q;
        float p = proto[k * 256 + c];
        s2 += p * p;
        d0 += p * wout[c];
        d1 += p * wout[256 + c];
    }
#pragma unroll
    for (int off = 32; off; off >>= 1) {
        s2 += __shfl_xor(s2, off);
        d0 += __shfl_xor(d0, off);
        d1 += __shfl_xor(d1, off);
    }
    if (l == 0) {
        float rinv = rsqrtf(s2);
        M[k] = make_float2(d0 * rinv, d1 * rinv);
    }
}

// one layer: hout = relu(hin @ W^T + b), hin/hout are swizzled [64][256] bf16 LDS tiles
__device__ __forceinline__ void layer(const unsigned short* hin, unsigned short* hout,
                                      const unsigned short* W, const float* __restrict__ bias,
                                      int lane, int wave) {
    const int l15 = lane & 15;
    const int g   = lane >> 4;        // 0..3
    const int jw  = wave * 64;        // this wave's 64-col chunk

    // acc[ri][ci]: output rows 16*ri + l15, cols jw + 16*ci + 4*g + r   (swapped-operand C layout)
    f32x4 acc[4][4];
#pragma unroll
    for (int ci = 0; ci < 4; ++ci) {
        const float4 bv = *reinterpret_cast<const float4*>(&bias[jw + 16 * ci + 4 * g]);
#pragma unroll
        for (int ri = 0; ri < 4; ++ri) {
            acc[ri][ci][0] = bv.x; acc[ri][ci][1] = bv.y;
            acc[ri][ci][2] = bv.z; acc[ri][ci][3] = bv.w;
        }
    }

    const char* hin_b = reinterpret_cast<const char*>(hin);
    // per-ci W fragment base: row j = jw + 16*ci + l15, k offset 8*g
    const unsigned short* wp[4];
#pragma unroll
    for (int ci = 0; ci < 4; ++ci)
        wp[ci] = W + (jw + 16 * ci + l15) * DHID + 8 * g;

#pragma unroll 2
    for (int kk = 0; kk < 8; ++kk) {
        const int k0 = kk * 32 + 8 * g;
        bf16x8 a[4], b[4];
#pragma unroll
        for (int ri = 0; ri < 4; ++ri)
            a[ri] = *reinterpret_cast<const bf16x8*>(hin_b + hswz(16 * ri + l15, k0));
#pragma unroll
        for (int ci = 0; ci < 4; ++ci)
            b[ci] = *reinterpret_cast<const bf16x8*>(wp[ci] + 32 * kk);
#pragma unroll
        for (int ri = 0; ri < 4; ++ri)
#pragma unroll
            for (int ci = 0; ci < 4; ++ci)
                // swapped operands: D[j][i] layout -> lane holds 4 consecutive COLS of one row
                acc[ri][ci] = __builtin_amdgcn_mfma_f32_16x16x32_bf16(b[ci], a[ri], acc[ri][ci], 0, 0, 0);
    }

    // epilogue: relu, bf16, packed 8B swizzled writes (4 consecutive cols per lane)
    char* hout_b = reinterpret_cast<char*>(hout);
#pragma unroll
    for (int ri = 0; ri < 4; ++ri) {
        const int row = 16 * ri + l15;
#pragma unroll
        for (int ci = 0; ci < 4; ++ci) {
            const int colb = jw + 16 * ci + 4 * g;
            unsigned long long pk =
                  (unsigned long long)f2b(fmaxf(acc[ri][ci][0], 0.f))
                | ((unsigned long long)f2b(fmaxf(acc[ri][ci][1], 0.f)) << 16)
                | ((unsigned long long)f2b(fmaxf(acc[ri][ci][2], 0.f)) << 32)
                | ((unsigned long long)f2b(fmaxf(acc[ri][ci][3], 0.f)) << 48);
            *reinterpret_cast<unsigned long long*>(hout_b + hswz(row, colb)) = pk;
        }
    }
}

__global__ __launch_bounds__(THREADS, 2) void mlp_fused(
    const float* __restrict__ X,
    const unsigned short* __restrict__ Wb,   // 3 * 65536 bf16
    const float* __restrict__ b0,
    const float* __restrict__ b1,
    const float* __restrict__ b2,
    const float2* __restrict__ M,
    const float* __restrict__ bout,
    float* __restrict__ out)
{
    __shared__ unsigned short hbuf[2][ROWS * DHID];   // 2 x 32 KB

    const int tid  = threadIdx.x;
    const int lane = tid & 63;
    const int wave = tid >> 6;
    const int row0 = blockIdx.x * ROWS;

    // ---- stage X tile -> hbuf[0] (bf16, swizzled) ----
#pragma unroll
    for (int it = 0; it < 16; ++it) {
        int idx = tid + (it << 8);          // 0..4095
        int r = idx >> 6;
        int c = (idx & 63) << 2;
        const float4 v = *reinterpret_cast<const float4*>(X + (size_t)(row0 + r) * DHID + c);
        unsigned long long pk =
              (unsigned long long)f2b(v.x)
            | ((unsigned long long)f2b(v.y) << 16)
            | ((unsigned long long)f2b(v.z) << 32)
            | ((unsigned long long)f2b(v.w) << 48);
        *reinterpret_cast<unsigned long long*>(reinterpret_cast<char*>(&hbuf[0][0]) + hswz(r, c)) = pk;
    }
    __syncthreads();

    layer(&hbuf[0][0], &hbuf[1][0], Wb,            b0, lane, wave);
    __syncthreads();
    layer(&hbuf[1][0], &hbuf[0][0], Wb + 65536,    b1, lane, wave);
    __syncthreads();
    layer(&hbuf[0][0], &hbuf[1][0], Wb + 2 * 65536, b2, lane, wave);
    __syncthreads();

    // ---- epilogue: out[i][d] = rsqrt(sum h3^2) * sum_k h3[i][k]*M[k][d] + bout[d] ----
    float* scratch = reinterpret_cast<float*>(&hbuf[0][0]);   // hbuf[0] is free now
    const char* h3b = reinterpret_cast<const char*>(&hbuf[1][0]);
    {
        int r = tid >> 2, q = tid & 3;
        float s2 = 0.f, d0 = 0.f, d1 = 0.f;
        for (int c = q * 64; c < q * 64 + 64; c += 4) {
            unsigned long long v = *reinterpret_cast<const unsigned long long*>(h3b + hswz(r, c));
#pragma unroll
            for (int t = 0; t < 4; ++t) {
                float f = __uint_as_float((unsigned)((v >> (16 * t)) & 0xffffu) << 16);
                float2 m = M[c + t];
                s2 += f * f;
                d0 += f * m.x;
                d1 += f * m.y;
            }
        }
        scratch[tid]       = s2;
        scratch[256 + tid] = d0;
        scratch[512 + tid] = d1;
    }
    __syncthreads();
    if (tid < 128) {
        int r = tid >> 1, dsel = tid & 1;
        int b = r << 2;
        float s  = scratch[b] + scratch[b + 1] + scratch[b + 2] + scratch[b + 3];
        const float* dp = scratch + 256 + (dsel << 8);
        float dd = dp[b] + dp[b + 1] + dp[b + 2] + dp[b + 3];
        out[(size_t)(row0 + r) * 2 + dsel] = dd * rsqrtf(s) + bout[dsel];
    }
}

extern "C" void kernel_launch(void* const* d_in, const int* in_sizes, int n_in,
                              void* d_out, int out_size, void* d_ws, size_t ws_size,
                              hipStream_t stream) {
    const float* X     = (const float*)d_in[0];
    const float* W_in  = (const float*)d_in[1];
    const float* b_in  = (const float*)d_in[2];
    const float* W_h1  = (const float*)d_in[3];
    const float* b_h1  = (const float*)d_in[4];
    const float* W_h2  = (const float*)d_in[5];
    const float* b_h2  = (const float*)d_in[6];
    const float* proto = (const float*)d_in[7];
    const float* W_out = (const float*)d_in[8];
    const float* b_out = (const float*)d_in[9];

    unsigned short* Wb = (unsigned short*)d_ws;                       // 3*65536 bf16 = 384 KB
    float2*         M  = (float2*)((char*)d_ws + 3 * 65536 * 2);      // 2 KB
    float*          out = (float*)d_out;

    conv_w<<<768, 256, 0, stream>>>(W_in, W_h1, W_h2, Wb);
    make_m<<<256, 64, 0, stream>>>(proto, W_out, M);
    mlp_fused<<<NROWS / ROWS, THREADS, 0, stream>>>(X, Wb, b_in, b_h1, b_h2, M, b_out, out);
}

// Round 2
// 77.698 us; speedup vs baseline: 1.8541x; 1.8541x over previous
//
#include <hip/hip_runtime.h>
#include <hip/hip_bf16.h>

#define DHID 256
#define ROWS 64
#define THREADS 512
#define NROWS 131072

typedef __attribute__((ext_vector_type(8))) __bf16 bf16x8;
typedef __attribute__((ext_vector_type(4))) float f32x4;

// f32 -> bf16 bits, round-to-nearest-even
__device__ __forceinline__ unsigned short f2b(float f) {
    union { float f; unsigned u; } x; x.f = f;
    unsigned r = x.u + 0x7fffu + ((x.u >> 16) & 1u);
    return (unsigned short)(r >> 16);
}

// swizzled byte offset within a [64][256] bf16 LDS tile (T2-style XOR swizzle)
__device__ __forceinline__ int hswz(int row, int col) {
    return ((row << 9) + (col << 1)) ^ ((row & 7) << 4);
}

// ---- prep 1: convert + repack the three 256x256 f32 weights into bf16
// fragment-contiguous layout: out[((c16*8 + kk)*64 + lane)*8 + e] =
//   W[c16*16 + (lane&15)][kk*32 + 8*(lane>>4) + e]
// so each wave's per-kk B-fragment load is one contiguous coalesced 1KB read.
__global__ void conv_w(const float* __restrict__ w0, const float* __restrict__ w1,
                       const float* __restrict__ w2, unsigned short* __restrict__ out) {
    int i = blockIdx.x * blockDim.x + threadIdx.x;   // 0..196607
    const float* src = (i < 65536) ? w0 : (i < 131072 ? w1 : w2);
    int rem  = i & 65535;
    int e    = rem & 7;
    int lane = (rem >> 3) & 63;
    int blk  = rem >> 9;          // c16*8 + kk
    int kk   = blk & 7;
    int c16  = blk >> 3;
    int row  = c16 * 16 + (lane & 15);
    int col  = kk * 32 + 8 * (lane >> 4) + e;
    out[i] = f2b(src[row * 256 + col]);
}

// ---- prep 2: M[k] = (dot(pn_k, Wout0), dot(pn_k, Wout1)), pn_k = proto_k/||proto_k|| ----
__global__ void make_m(const float* __restrict__ proto, const float* __restrict__ wout,
                       float2* __restrict__ M) {
    int k = blockIdx.x;       // 0..255
    int l = threadIdx.x;      // 0..63
    float s2 = 0.f, d0 = 0.f, d1 = 0.f;
#pragma unroll
    for (int q = 0; q < 4; ++q) {
        int c = l + 64 * q;
        float p = proto[k * 256 + c];
        s2 += p * p;
        d0 += p * wout[c];
        d1 += p * wout[256 + c];
    }
#pragma unroll
    for (int off = 32; off; off >>= 1) {
        s2 += __shfl_xor(s2, off);
        d0 += __shfl_xor(d0, off);
        d1 += __shfl_xor(d1, off);
    }
    if (l == 0) {
        float rinv = rsqrtf(s2);
        M[k] = make_float2(d0 * rinv, d1 * rinv);
    }
}

// one layer: hout = relu(hin @ W^T + b); hin/hout swizzled [64][256] bf16 LDS tiles.
// W is in fragment-contiguous repacked layout. Wave handles 32 output cols.
__device__ __forceinline__ void layer(const unsigned short* hin, unsigned short* hout,
                                      const unsigned short* W, const float* __restrict__ bias,
                                      int lane, int wave) {
    const int l15 = lane & 15;
    const int g   = lane >> 4;        // 0..3
    const int jw  = wave * 32;        // this wave's 32-col chunk

    f32x4 acc[4][2];
#pragma unroll
    for (int ci = 0; ci < 2; ++ci) {
        const float4 bv = *reinterpret_cast<const float4*>(&bias[jw + 16 * ci + 4 * g]);
#pragma unroll
        for (int ri = 0; ri < 4; ++ri) {
            acc[ri][ci][0] = bv.x; acc[ri][ci][1] = bv.y;
            acc[ri][ci][2] = bv.z; acc[ri][ci][3] = bv.w;
        }
    }

    const char* hin_b = reinterpret_cast<const char*>(hin);
    const unsigned short* wp[2];
#pragma unroll
    for (int ci = 0; ci < 2; ++ci)
        wp[ci] = W + ((wave * 2 + ci) * 8) * 512 + lane * 8;   // kk=0 fragment base

    bf16x8 bcur[2];
#pragma unroll
    for (int ci = 0; ci < 2; ++ci) bcur[ci] = *reinterpret_cast<const bf16x8*>(wp[ci]);

#pragma unroll
    for (int kk = 0; kk < 8; ++kk) {
        const int k0 = kk * 32 + 8 * g;
        bf16x8 a[4];
#pragma unroll
        for (int ri = 0; ri < 4; ++ri)
            a[ri] = *reinterpret_cast<const bf16x8*>(hin_b + hswz(16 * ri + l15, k0));
        bf16x8 bnxt[2];
        if (kk < 7) {
#pragma unroll
            for (int ci = 0; ci < 2; ++ci)
                bnxt[ci] = *reinterpret_cast<const bf16x8*>(wp[ci] + (kk + 1) * 512);
        }
#pragma unroll
        for (int ri = 0; ri < 4; ++ri)
#pragma unroll
            for (int ci = 0; ci < 2; ++ci)
                acc[ri][ci] = __builtin_amdgcn_mfma_f32_16x16x32_bf16(bcur[ci], a[ri], acc[ri][ci], 0, 0, 0);
        if (kk < 7) { bcur[0] = bnxt[0]; bcur[1] = bnxt[1]; }
    }

    // epilogue: relu, bf16, packed 8B swizzled writes (4 consecutive cols per lane)
    char* hout_b = reinterpret_cast<char*>(hout);
#pragma unroll
    for (int ri = 0; ri < 4; ++ri) {
        const int row = 16 * ri + l15;
#pragma unroll
        for (int ci = 0; ci < 2; ++ci) {
            const int colb = jw + 16 * ci + 4 * g;
            unsigned long long pk =
                  (unsigned long long)f2b(fmaxf(acc[ri][ci][0], 0.f))
                | ((unsigned long long)f2b(fmaxf(acc[ri][ci][1], 0.f)) << 16)
                | ((unsigned long long)f2b(fmaxf(acc[ri][ci][2], 0.f)) << 32)
                | ((unsigned long long)f2b(fmaxf(acc[ri][ci][3], 0.f)) << 48);
            *reinterpret_cast<unsigned long long*>(hout_b + hswz(row, colb)) = pk;
        }
    }
}

// layer 3 fused with the normalize+project epilogue: never materializes h3.
// part: float[3][64][8] partials (s2, d0, d1) per (row, wave).
__device__ __forceinline__ void layer3_reduce(const unsigned short* hin,
                                              const unsigned short* W,
                                              const float* __restrict__ bias,
                                              const float2* __restrict__ M,
                                              float* part, int lane, int wave) {
    const int l15 = lane & 15;
    const int g   = lane >> 4;
    const int jw  = wave * 32;

    f32x4 acc[4][2];
#pragma unroll
    for (int ci = 0; ci < 2; ++ci) {
        const float4 bv = *reinterpret_cast<const float4*>(&bias[jw + 16 * ci + 4 * g]);
#pragma unroll
        for (int ri = 0; ri < 4; ++ri) {
            acc[ri][ci][0] = bv.x; acc[ri][ci][1] = bv.y;
            acc[ri][ci][2] = bv.z; acc[ri][ci][3] = bv.w;
        }
    }

    const char* hin_b = reinterpret_cast<const char*>(hin);
    const unsigned short* wp[2];
#pragma unroll
    for (int ci = 0; ci < 2; ++ci)
        wp[ci] = W + ((wave * 2 + ci) * 8) * 512 + lane * 8;

    bf16x8 bcur[2];
#pragma unroll
    for (int ci = 0; ci < 2; ++ci) bcur[ci] = *reinterpret_cast<const bf16x8*>(wp[ci]);

#pragma unroll
    for (int kk = 0; kk < 8; ++kk) {
        const int k0 = kk * 32 + 8 * g;
        bf16x8 a[4];
#pragma unroll
        for (int ri = 0; ri < 4; ++ri)
            a[ri] = *reinterpret_cast<const bf16x8*>(hin_b + hswz(16 * ri + l15, k0));
        bf16x8 bnxt[2];
        if (kk < 7) {
#pragma unroll
            for (int ci = 0; ci < 2; ++ci)
                bnxt[ci] = *reinterpret_cast<const bf16x8*>(wp[ci] + (kk + 1) * 512);
        }
#pragma unroll
        for (int ri = 0; ri < 4; ++ri)
#pragma unroll
            for (int ci = 0; ci < 2; ++ci)
                acc[ri][ci] = __builtin_amdgcn_mfma_f32_16x16x32_bf16(bcur[ci], a[ri], acc[ri][ci], 0, 0, 0);
        if (kk < 7) { bcur[0] = bnxt[0]; bcur[1] = bnxt[1]; }
    }

    // fused epilogue: h = relu(acc) in fp32; per-row partials of ||h||^2 and h@M
    float2 m[2][4];
#pragma unroll
    for (int ci = 0; ci < 2; ++ci)
#pragma unroll
        for (int e = 0; e < 4; ++e)
            m[ci][e] = M[jw + 16 * ci + 4 * g + e];

    float s2[4], d0[4], d1[4];
#pragma unroll
    for (int ri = 0; ri < 4; ++ri) {
        s2[ri] = 0.f; d0[ri] = 0.f; d1[ri] = 0.f;
#pragma unroll
        for (int ci = 0; ci < 2; ++ci)
#pragma unroll
            for (int e = 0; e < 4; ++e) {
                float h = fmaxf(acc[ri][ci][e], 0.f);
                s2[ri] += h * h;
                d0[ri] += h * m[ci][e].x;
                d1[ri] += h * m[ci][e].y;
            }
    }
    // reduce across the 4 g-lanes sharing each row (lanes l15, l15+16, l15+32, l15+48)
#pragma unroll
    for (int ri = 0; ri < 4; ++ri) {
        s2[ri] += __shfl_xor(s2[ri], 16); s2[ri] += __shfl_xor(s2[ri], 32);
        d0[ri] += __shfl_xor(d0[ri], 16); d0[ri] += __shfl_xor(d0[ri], 32);
        d1[ri] += __shfl_xor(d1[ri], 16); d1[ri] += __shfl_xor(d1[ri], 32);
    }
    if (lane < 16) {
#pragma unroll
        for (int ri = 0; ri < 4; ++ri) {
            int r = 16 * ri + l15;
            part[r * 8 + wave]        = s2[ri];
            part[512 + r * 8 + wave]  = d0[ri];
            part[1024 + r * 8 + wave] = d1[ri];
        }
    }
}

__global__ __launch_bounds__(THREADS, 4) void mlp_fused(
    const float* __restrict__ X,
    const unsigned short* __restrict__ Wb,   // 3 * 65536 bf16, repacked
    const float* __restrict__ b0,
    const float* __restrict__ b1,
    const float* __restrict__ b2,
    const float2* __restrict__ M,
    const float* __restrict__ bout,
    float* __restrict__ out)
{
    __shared__ unsigned short hbuf[2][ROWS * DHID];   // 2 x 32 KB

    const int tid  = threadIdx.x;
    const int lane = tid & 63;
    const int wave = tid >> 6;
    const int row0 = blockIdx.x * ROWS;

    // ---- stage X tile -> hbuf[0] (bf16, swizzled) ----
#pragma unroll
    for (int it = 0; it < 8; ++it) {
        int idx = tid + (it << 9);          // 0..4095
        int r = idx >> 6;
        int c = (idx & 63) << 2;
        const float4 v = *reinterpret_cast<const float4*>(X + (size_t)(row0 + r) * DHID + c);
        unsigned long long pk =
              (unsigned long long)f2b(v.x)
            | ((unsigned long long)f2b(v.y) << 16)
            | ((unsigned long long)f2b(v.z) << 32)
            | ((unsigned long long)f2b(v.w) << 48);
        *reinterpret_cast<unsigned long long*>(reinterpret_cast<char*>(&hbuf[0][0]) + hswz(r, c)) = pk;
    }
    __syncthreads();

    layer(&hbuf[0][0], &hbuf[1][0], Wb,             b0, lane, wave);
    __syncthreads();
    layer(&hbuf[1][0], &hbuf[0][0], Wb + 65536,     b1, lane, wave);
    __syncthreads();
    float* part = reinterpret_cast<float*>(&hbuf[1][0]);   // 6 KB partials
    layer3_reduce(&hbuf[0][0], Wb + 2 * 65536, b2, M, part, lane, wave);
    __syncthreads();

    if (tid < 128) {
        int r = tid >> 1, dsel = tid & 1;
        float s = 0.f, dd = 0.f;
        const float* ps = part + r * 8;
        const float* pd = part + 512 + dsel * 512 + r * 8;
#pragma unroll
        for (int w = 0; w < 8; ++w) { s += ps[w]; dd += pd[w]; }
        out[(size_t)(row0 + r) * 2 + dsel] = dd * rsqrtf(s) + bout[dsel];
    }
}

extern "C" void kernel_launch(void* const* d_in, const int* in_sizes, int n_in,
                              void* d_out, int out_size, void* d_ws, size_t ws_size,
                              hipStream_t stream) {
    const float* X     = (const float*)d_in[0];
    const float* W_in  = (const float*)d_in[1];
    const float* b_in  = (const float*)d_in[2];
    const float* W_h1  = (const float*)d_in[3];
    const float* b_h1  = (const float*)d_in[4];
    const float* W_h2  = (const float*)d_in[5];
    const float* b_h2  = (const float*)d_in[6];
    const float* proto = (const float*)d_in[7];
    const float* W_out = (const float*)d_in[8];
    const float* b_out = (const float*)d_in[9];

    unsigned short* Wb = (unsigned short*)d_ws;                       // 3*65536 bf16 = 384 KB
    float2*         M  = (float2*)((char*)d_ws + 3 * 65536 * 2);      // 2 KB
    float*          out = (float*)d_out;

    conv_w<<<768, 256, 0, stream>>>(W_in, W_h1, W_h2, Wb);
    make_m<<<256, 64, 0, stream>>>(proto, W_out, M);
    mlp_fused<<<NROWS / ROWS, THREADS, 0, stream>>>(X, Wb, b_in, b_h1, b_h2, M, b_out, out);
}